// Round 9
// baseline (254.045 us; speedup 1.0000x reference)
//
#include <hip/hip_runtime.h>

typedef float f32x4_t __attribute__((ext_vector_type(4)));
typedef int i32x4_t __attribute__((ext_vector_type(4)));
typedef __bf16 bf16x8_t __attribute__((ext_vector_type(8)));
typedef unsigned short u16x8_t __attribute__((ext_vector_type(8)));

// ---- geometry ----
#define NPIX        100352      // 32*56*56
#define PIX_PER_IMG 3136        // 56*56
#define PH          58
#define PPIX        3364        // 58*58
#define C_IN        128
#define C_OUT       256
#define NTAPS       9
#define NV4         3211264     // x as float4 count
#define NWELEM      294912      // 3*3*128*256
#define MTILES      392         // NPIX/256
#define NPADPIX     107648      // 32*58*58

// ---- ws byte offsets ----
#define OFF_ENC     0           // 4 x u32
#define OFF_SCALE   64          // 256 f32
#define OFF_BIAS    1152        // 256 f32
#define OFF_J1TAP   2176        // 9*256 f32 = 9216 B
#define OFF_J1ALL   11392       // 256 f32
#define OFF_WT      16384       // 589824 B bf16 [9][256 f][128 c]
#define OFF_WQT8    606208      // 294912 B i8 [9][256 f][128 c]
#define OFF_PSUM    901120      // 784*128 f32
#define OFF_PSQ     1302528     // 784*128 f32
#define OFF_K1      1703936     // 100352 f32 (box-summed k' sums per out pixel)
#define OFF_SCP     2105344     // 107648 f32 (per padded pixel channel-sum of k')
#define OFF_XPAD    2535936     // 27557888 B bf16 [32][58][58][128]
#define OFF_XQ8     30093824    // 13778944 B i8  [32][58][58][128]  (end ~43.9MB)

// ---- helpers ----
__device__ __forceinline__ unsigned short f2bf(float x) {
  unsigned u = __float_as_uint(x);
  u += 0x7FFFu + ((u >> 16) & 1u);   // RNE
  return (unsigned short)(u >> 16);
}
__device__ __forceinline__ unsigned encf(float v) {
  unsigned u = __float_as_uint(v);
  return (u & 0x80000000u) ? ~u : (u | 0x80000000u);
}
__device__ __forceinline__ float decf(unsigned e) {
  unsigned u = (e & 0x80000000u) ? (e ^ 0x80000000u) : ~e;
  return __uint_as_float(u);
}
__device__ __forceinline__ void gl_lds16(const void* g, void* l) {
  auto gp = (const __attribute__((address_space(1))) unsigned*)(const unsigned*)g;
  auto lp = (__attribute__((address_space(3))) unsigned*)(unsigned*)l;
  __builtin_amdgcn_global_load_lds(gp, lp, 16, 0, 0);
}
#define SCHED_FENCE() __builtin_amdgcn_sched_barrier(0)

// ---- kernels ----
__global__ void kinit(unsigned* enc) {
  enc[0] = 0xFFFFFFFFu; enc[1] = 0u;   // x min/max encodings
  enc[2] = 0xFFFFFFFFu; enc[3] = 0u;   // wfold min/max encodings
}

__global__ void kminmax(const float4* __restrict__ x, unsigned* __restrict__ enc) {
  const int tid = blockIdx.x * blockDim.x + threadIdx.x;
  const int stride = gridDim.x * blockDim.x;
  float mn = 3.4e38f, mx = -3.4e38f;
  for (int i = tid; i < NV4; i += stride) {
    float4 v = x[i];
    mn = fminf(mn, fminf(fminf(v.x, v.y), fminf(v.z, v.w)));
    mx = fmaxf(mx, fmaxf(fmaxf(v.x, v.y), fmaxf(v.z, v.w)));
  }
  #pragma unroll
  for (int off = 32; off > 0; off >>= 1) {
    mn = fminf(mn, __shfl_xor(mn, off));
    mx = fmaxf(mx, __shfl_xor(mx, off));
  }
  __shared__ float smn[4], smx[4];
  const int lane = threadIdx.x & 63, w = threadIdx.x >> 6;
  if (lane == 0) { smn[w] = mn; smx[w] = mx; }
  __syncthreads();
  if (threadIdx.x == 0) {
    mn = fminf(fminf(smn[0], smn[1]), fminf(smn[2], smn[3]));
    mx = fmaxf(fmaxf(smx[0], smx[1]), fmaxf(smx[2], smx[3]));
    atomicMin(&enc[0], encf(mn));
    atomicMax(&enc[1], encf(mx));
  }
}

// W [3][3][128][256] f32 -> Wt [tap][256 f][128 c] bf16
__global__ void kwconv(const float* __restrict__ W, unsigned short* __restrict__ wt) {
  const int idx = blockIdx.x * 256 + threadIdx.x;
  if (idx >= NWELEM) return;
  const int c = idx & 127;
  const int f = (idx >> 7) & 255;
  const int tap = idx >> 15;
  wt[idx] = f2bf(W[(tap * 128 + c) * 256 + f]);
}

// quantized folded weight CODES j' = rint((v-wmn)*wrstep)-128 (i8) + per-(tap,f) code sums
__global__ __launch_bounds__(256)
void kwq(const float* __restrict__ W, const float* __restrict__ scale,
         const unsigned* __restrict__ enc, signed char* __restrict__ wq8,
         float* __restrict__ j1tap) {
  const int idx = blockIdx.x * 256 + threadIdx.x;
  const int c = idx & 127;
  const int f = (idx >> 7) & 255;
  const int tap = idx >> 15;
  const float wmn = decf(enc[2]), wmx = decf(enc[3]);
  const float wrstep = 255.0f / (wmx - wmn);
  const float v = W[(tap * 128 + c) * 256 + f] * scale[f];
  const int code = (int)rintf((v - wmn) * wrstep) - 128;
  wq8[idx] = (signed char)code;
  // reduce code over the 128 c's of this block's two f-columns
  float p = (float)code;
  #pragma unroll
  for (int off = 32; off > 0; off >>= 1) p += __shfl_xor(p, off);
  __shared__ float sb[4];
  const int lane = threadIdx.x & 63, wv = threadIdx.x >> 6;
  if (lane == 0) sb[wv] = p;
  __syncthreads();
  if (threadIdx.x == 0)   j1tap[tap * 256 + f] = sb[0] + sb[1];
  if (threadIdx.x == 128) j1tap[tap * 256 + f] = sb[2] + sb[3];
}

__global__ void kjall(const float* __restrict__ j1tap, float* __restrict__ j1all) {
  const int f = threadIdx.x;
  float s = 0.f;
  #pragma unroll
  for (int t = 0; t < 9; ++t) s += j1tap[t * 256 + f];
  j1all[f] = s;
}

// pad-fill: x f32 -> xpad bf16 (zero border), xq8 i8 codes k'=k-128 (0 at border),
// scp = per padded pixel channel-sum of k' (0 at border)
__global__ void kpadfill(const float* __restrict__ x, const unsigned* __restrict__ enc,
                         unsigned short* __restrict__ xpad, signed char* __restrict__ xq8,
                         float* __restrict__ scp)
{
  const int tid = blockIdx.x * 256 + threadIdx.x;
  if (tid >= NPADPIX * 16) return;
  const int pp = tid >> 4;
  const int c8 = (tid & 15) << 3;
  const int n = pp / PPIX;
  const int rem = pp - n * PPIX;
  const int hp = rem / PH;
  const int wp = rem - hp * PH;
  u16x8_t vb;
  int codes[8];
  #pragma unroll
  for (int j = 0; j < 8; ++j) { vb[j] = 0; codes[j] = 0; }
  float csum = 0.f;
  if (hp >= 1 && hp <= 56 && wp >= 1 && wp <= 56) {
    const float mn = decf(enc[0]), mx = decf(enc[1]);
    const float rstep = 255.0f / (mx - mn);
    const float* src = x + ((n * PIX_PER_IMG) + (hp - 1) * 56 + (wp - 1)) * C_IN + c8;
    const float4 a = *(const float4*)src;
    const float4 b = *(const float4*)(src + 4);
    const float v[8] = {a.x, a.y, a.z, a.w, b.x, b.y, b.z, b.w};
    #pragma unroll
    for (int j = 0; j < 8; ++j) {
      vb[j] = f2bf(v[j]);
      const int k = (int)rintf((v[j] - mn) * rstep);
      codes[j] = k - 128;
      csum += (float)(k - 128);
    }
  }
  *(u16x8_t*)(xpad + pp * C_IN + c8) = vb;
  unsigned long long pk = 0;
  #pragma unroll
  for (int j = 0; j < 8; ++j)
    pk |= ((unsigned long long)(unsigned char)(signed char)codes[j]) << (8 * j);
  *(unsigned long long*)(xq8 + pp * C_IN + c8) = pk;
  // reduce channel sum across the 16 threads of this pixel
  csum += __shfl_xor(csum, 1, 16);
  csum += __shfl_xor(csum, 2, 16);
  csum += __shfl_xor(csum, 4, 16);
  csum += __shfl_xor(csum, 8, 16);
  if ((threadIdx.x & 15) == 0) scp[pp] = csum;
}

// 3x3 box sum of scp -> K1 per output pixel
__global__ __launch_bounds__(256)
void kbox(const float* __restrict__ scp, float* __restrict__ k1) {
  const int pix = blockIdx.x * 256 + threadIdx.x;
  if (pix >= NPIX) return;
  const int n = pix / PIX_PER_IMG;
  const int rem = pix - n * PIX_PER_IMG;
  const int h = rem / 56;
  const int w = rem - h * 56;
  const float* base = scp + n * PPIX + h * PH + w;
  float s = 0.f;
  #pragma unroll
  for (int dh = 0; dh < 3; ++dh)
    #pragma unroll
    for (int dw = 0; dw < 3; ++dw)
      s += base[dh * PH + dw];
  k1[pix] = s;
}

// ===== conv1 (stats): bf16, BM=256 BN=128 BK=32, 2 blocks/CU, counted vmcnt (R8-proven) =====
__global__ __launch_bounds__(512, 4)
void kconvS(const unsigned short* __restrict__ xin,   // padded bf16
            const unsigned short* __restrict__ wt,    // bf16 [9][256][128]
            float* __restrict__ psum, float* __restrict__ psq)
{
  const int bid = blockIdx.x;
  const int slot = (bid & 7) * 98 + (bid >> 3);
  const int bm = slot >> 1;
  const int bn = slot & 1;

  const int tid = threadIdx.x;
  const int lane = tid & 63;
  const int wid = tid >> 6;
  const int wm = wid >> 1;
  const int wn = wid & 1;
  const int l16 = lane & 15;
  const int rsub = lane >> 4;

  __shared__ __align__(16) unsigned char smem[49152];

  unsigned aoff[2];
  {
    const int arow0 = wid * 8 + (lane >> 3);
    const int pc = lane & 7;
    #pragma unroll
    for (int j = 0; j < 2; ++j) {
      const int row = j * 64 + arow0;
      const int lc = pc ^ (row & 7);
      const int pix = bm * 256 + row + 128 * (lc >> 2);
      const int n = pix / PIX_PER_IMG;
      const int rem = pix - n * PIX_PER_IMG;
      const int hh = rem / 56;
      const int ww = rem - hh * 56;
      aoff[j] = (unsigned)((n * PPIX + hh * PH + ww) * C_IN + (lc & 3) * 8);
    }
  }
  unsigned boff;
  {
    const int row = wid * 8 + (lane >> 3);
    const int pc = lane & 7;
    const int lc = pc ^ (row & 7);
    const int f = bn * 128 + row + 64 * (lc >> 2);
    boff = (unsigned)(f * C_IN + (lc & 3) * 8);
  }

  int a_rd[4], b_rd[4];
  #pragma unroll
  for (int im = 0; im < 4; ++im) {
    const int p = wm * 64 + im * 16 + l16;
    const int row = p & 127, half = p >> 7;
    const int phys = (half * 4 + rsub) ^ (row & 7);
    a_rd[im] = row * 128 + phys * 16;
  }
  #pragma unroll
  for (int in = 0; in < 4; ++in) {
    const int f = wn * 64 + in * 16 + l16;
    const int row = f & 63, half = f >> 6;
    const int phys = (half * 4 + rsub) ^ (row & 7);
    b_rd[in] = row * 128 + phys * 16;
  }

  f32x4_t acc[4][4];
  #pragma unroll
  for (int im = 0; im < 4; ++im)
    #pragma unroll
    for (int in = 0; in < 4; ++in)
      #pragma unroll
      for (int j = 0; j < 4; ++j) acc[im][in][j] = 0.f;

  auto stage = [&](int s) {
    const int tap = s >> 2;
    const int cq = (s & 3) * 32;
    const int kh = tap / 3, kw = tap - kh * 3;
    const unsigned atap = (unsigned)((kh * PH + kw) * C_IN + cq);
    const unsigned btap = (unsigned)(tap * (C_OUT * C_IN) + cq);
    unsigned char* sA = smem + (s & 1) * 24576;
    unsigned char* sB = sA + 16384;
    gl_lds16(xin + atap + aoff[0], sA + wid * 1024);
    gl_lds16(xin + atap + aoff[1], sA + 8192 + wid * 1024);
    gl_lds16(wt + btap + boff, sB + wid * 1024);
  };

  auto compute = [&](int s) {
    const unsigned char* sA = smem + (s & 1) * 24576;
    const unsigned char* sB = sA + 16384;
    bf16x8_t av[4], bv[4];
    #pragma unroll
    for (int im = 0; im < 4; ++im) av[im] = *(const bf16x8_t*)(sA + a_rd[im]);
    #pragma unroll
    for (int in = 0; in < 4; ++in) bv[in] = *(const bf16x8_t*)(sB + b_rd[in]);
    #pragma unroll
    for (int im = 0; im < 4; ++im)
      #pragma unroll
      for (int in = 0; in < 4; ++in)
        acc[im][in] = __builtin_amdgcn_mfma_f32_16x16x32_bf16(av[im], bv[in], acc[im][in], 0, 0, 0);
  };

  stage(0); stage(1);
  #pragma unroll 1
  for (int s = 0; s < 35; ++s) {
    asm volatile("s_waitcnt vmcnt(3)" ::: "memory");
    SCHED_FENCE();
    __builtin_amdgcn_s_barrier();
    SCHED_FENCE();
    compute(s);
    SCHED_FENCE();
    __builtin_amdgcn_s_barrier();
    SCHED_FENCE();
    if (s < 34) stage(s + 2);
  }
  asm volatile("s_waitcnt vmcnt(0)" ::: "memory");
  SCHED_FENCE();
  __builtin_amdgcn_s_barrier();
  SCHED_FENCE();
  compute(35);

  __syncthreads();
  float* sb = (float*)smem;
  #pragma unroll
  for (int in = 0; in < 4; ++in) {
    float s = 0.f, q = 0.f;
    #pragma unroll
    for (int im = 0; im < 4; ++im)
      #pragma unroll
      for (int j = 0; j < 4; ++j) {
        const float v = acc[im][in][j];
        s += v; q += v * v;
      }
    s += __shfl_xor(s, 16); q += __shfl_xor(q, 16);
    s += __shfl_xor(s, 32); q += __shfl_xor(q, 32);
    if (lane < 16) {
      sb[wid * 64 + in * 16 + lane] = s;
      sb[512 + wid * 64 + in * 16 + lane] = q;
    }
  }
  __syncthreads();
  if (tid < 128) {
    const int wn2 = tid >> 6, cl = tid & 63;
    float s = 0.f, q = 0.f;
    #pragma unroll
    for (int wm2 = 0; wm2 < 4; ++wm2) {
      s += sb[(wm2 * 2 + wn2) * 64 + cl];
      q += sb[512 + (wm2 * 2 + wn2) * 64 + cl];
    }
    psum[(bm * 2 + bn) * 128 + tid] = s;
    psq[(bm * 2 + bn) * 128 + tid] = q;
  }
}

// ===== conv2: int8 codes, mfma_i32_16x16x64_i8, BK=64 (18 tiles), same structure =====
__global__ __launch_bounds__(512, 4)
void kconv2(const signed char* __restrict__ xq8,    // padded codes [32][58][58][128]
            const signed char* __restrict__ wq8,    // codes [9][256 f][128 c]
            float* __restrict__ out,
            const float* __restrict__ bias,
            const float* __restrict__ k1,
            const float* __restrict__ j1tap,
            const float* __restrict__ j1all,
            const unsigned* __restrict__ enc)
{
  const int bid = blockIdx.x;
  const int slot = (bid & 7) * 98 + (bid >> 3);
  const int bm = slot >> 1;
  const int bn = slot & 1;

  const int tid = threadIdx.x;
  const int lane = tid & 63;
  const int wid = tid >> 6;
  const int wm = wid >> 1;
  const int wn = wid & 1;
  const int l16 = lane & 15;
  const int rsub = lane >> 4;          // K 16B-chunk, 0..3

  __shared__ __align__(16) unsigned char smem[49152];   // 2 x (A 16KB + B 8KB)

  // byte-based staging offsets (pixel row = 64B of codes; rows pack {r, r+128})
  unsigned aoff[2];
  {
    const int arow0 = wid * 8 + (lane >> 3);
    const int pc = lane & 7;
    #pragma unroll
    for (int j = 0; j < 2; ++j) {
      const int row = j * 64 + arow0;
      const int lc = pc ^ (row & 7);
      const int pix = bm * 256 + row + 128 * (lc >> 2);
      const int n = pix / PIX_PER_IMG;
      const int rem = pix - n * PIX_PER_IMG;
      const int hh = rem / 56;
      const int ww = rem - hh * 56;
      aoff[j] = (unsigned)((n * PPIX + hh * PH + ww) * 128 + (lc & 3) * 16);
    }
  }
  unsigned boff;
  {
    const int row = wid * 8 + (lane >> 3);
    const int pc = lane & 7;
    const int lc = pc ^ (row & 7);
    const int f = bn * 128 + row + 64 * (lc >> 2);
    boff = (unsigned)(f * 128 + (lc & 3) * 16);
  }

  int a_rd[4], b_rd[4];
  #pragma unroll
  for (int im = 0; im < 4; ++im) {
    const int p = wm * 64 + im * 16 + l16;
    const int row = p & 127, half = p >> 7;
    const int phys = (half * 4 + rsub) ^ (row & 7);
    a_rd[im] = row * 128 + phys * 16;
  }
  #pragma unroll
  for (int in = 0; in < 4; ++in) {
    const int f = wn * 64 + in * 16 + l16;
    const int row = f & 63, half = f >> 6;
    const int phys = (half * 4 + rsub) ^ (row & 7);
    b_rd[in] = row * 128 + phys * 16;
  }

  i32x4_t acc[4][4];
  #pragma unroll
  for (int im = 0; im < 4; ++im)
    #pragma unroll
    for (int in = 0; in < 4; ++in)
      #pragma unroll
      for (int j = 0; j < 4; ++j) acc[im][in][j] = 0;

  auto stage = [&](int s) {
    const int tap = s >> 1;
    const int ch64 = (s & 1) << 6;
    const int kh = tap / 3, kw = tap - kh * 3;
    const unsigned atap = (unsigned)((kh * PH + kw) * 128 + ch64);
    const unsigned btap = (unsigned)(tap * (C_OUT * 128) + ch64);
    unsigned char* sA = smem + (s & 1) * 24576;
    unsigned char* sB = sA + 16384;
    gl_lds16(xq8 + atap + aoff[0], sA + wid * 1024);
    gl_lds16(xq8 + atap + aoff[1], sA + 8192 + wid * 1024);
    gl_lds16(wq8 + btap + boff, sB + wid * 1024);
  };

  auto compute = [&](int s) {
    const unsigned char* sA = smem + (s & 1) * 24576;
    const unsigned char* sB = sA + 16384;
    i32x4_t av[4], bv[4];
    #pragma unroll
    for (int im = 0; im < 4; ++im) av[im] = *(const i32x4_t*)(sA + a_rd[im]);
    #pragma unroll
    for (int in = 0; in < 4; ++in) bv[in] = *(const i32x4_t*)(sB + b_rd[in]);
    #pragma unroll
    for (int im = 0; im < 4; ++im)
      #pragma unroll
      for (int in = 0; in < 4; ++in)
        acc[im][in] = __builtin_amdgcn_mfma_i32_16x16x64_i8(av[im], bv[in], acc[im][in], 0, 0, 0);
  };

  stage(0); stage(1);
  #pragma unroll 1
  for (int s = 0; s < 17; ++s) {
    asm volatile("s_waitcnt vmcnt(3)" ::: "memory");
    SCHED_FENCE();
    __builtin_amdgcn_s_barrier();
    SCHED_FENCE();
    compute(s);
    SCHED_FENCE();
    __builtin_amdgcn_s_barrier();
    SCHED_FENCE();
    if (s < 16) stage(s + 2);
  }
  asm volatile("s_waitcnt vmcnt(0)" ::: "memory");
  SCHED_FENCE();
  __builtin_amdgcn_s_barrier();
  SCHED_FENCE();
  compute(17);

  // ---- epilogue: out = relu(sxw*(KJ + b'*K1 + a'*Jv + a'*b'*128*ntap) + bias) ----
  const float xmn = decf(enc[0]), xmx = decf(enc[1]);
  const float sx = (xmx - xmn) / 255.0f;
  const float wmn = decf(enc[2]), wmx = decf(enc[3]);
  const float sw = (wmx - wmn) / 255.0f;
  const float ap = xmn / sx + 128.0f;
  const float bp = wmn / sw + 128.0f;
  const float sxw = sx * sw;

  float biasv[4], j1av[4];
  int fidx[4];
  #pragma unroll
  for (int in = 0; in < 4; ++in) {
    fidx[in] = bn * 128 + wn * 64 + in * 16 + l16;
    biasv[in] = bias[fidx[in]];
    j1av[in] = j1all[fidx[in]];
  }

  #pragma unroll
  for (int im = 0; im < 4; ++im) {
    const int pixbase = bm * 256 + wm * 64 + im * 16 + rsub * 4;
    const float4 k1v = *(const float4*)(k1 + pixbase);
    #pragma unroll
    for (int j = 0; j < 4; ++j) {
      const int pix = pixbase + j;
      const int n = pix / PIX_PER_IMG;
      const int rem = pix - n * PIX_PER_IMG;
      const int h = rem / 56;
      const int w = rem - h * 56;
      const int khl = (h == 0) ? 1 : 0;
      const int khh = (h == 55) ? 1 : 2;
      const int kwl = (w == 0) ? 1 : 0;
      const int kwh = (w == 55) ? 1 : 2;
      const int ntap = (khh - khl + 1) * (kwh - kwl + 1);
      const float k1s = (j == 0) ? k1v.x : (j == 1) ? k1v.y : (j == 2) ? k1v.z : k1v.w;
      const float base_corr = bp * k1s + ap * bp * (float)(ntap << 7);
      #pragma unroll
      for (int in = 0; in < 4; ++in) {
        float jv;
        if (ntap == 9) {
          jv = j1av[in];
        } else {
          jv = 0.f;
          for (int kh = khl; kh <= khh; ++kh)
            for (int kw = kwl; kw <= kwh; ++kw)
              jv += j1tap[(kh * 3 + kw) * 256 + fidx[in]];
        }
        const float r = sxw * ((float)acc[im][in][j] + base_corr + ap * jv) + biasv[in];
        out[pix * 256 + fidx[in]] = fmaxf(r, 0.f);
      }
    }
  }
}

// per-channel stats: one block per channel
__global__ __launch_bounds__(256)
void kstats(const float* __restrict__ psum, const float* __restrict__ psq,
            const float* __restrict__ gamma, const float* __restrict__ beta,
            float* __restrict__ scale, float* __restrict__ bias)
{
  const int ch = blockIdx.x;
  const int bn = ch >> 7, col = ch & 127;
  float s = 0.f, q = 0.f;
  for (int bm = threadIdx.x; bm < MTILES; bm += 256) {
    s += psum[(bm * 2 + bn) * 128 + col];
    q += psq[(bm * 2 + bn) * 128 + col];
  }
  #pragma unroll
  for (int off = 32; off > 0; off >>= 1) {
    s += __shfl_xor(s, off);
    q += __shfl_xor(q, off);
  }
  __shared__ float ss[4], sq2[4];
  const int lane = threadIdx.x & 63, w = threadIdx.x >> 6;
  if (lane == 0) { ss[w] = s; sq2[w] = q; }
  __syncthreads();
  if (threadIdx.x == 0) {
    s = ss[0] + ss[1] + ss[2] + ss[3];
    q = sq2[0] + sq2[1] + sq2[2] + sq2[3];
    const float inv = 1.0f / (float)NPIX;
    const float mean = s * inv;
    const float var = q * inv - mean * mean;
    const float istd = 1.0f / sqrtf(var + 1e-5f);
    const float g = gamma[ch];
    scale[ch] = g * istd;
    bias[ch] = beta[ch] - g * mean * istd;
  }
}

// w_fold min/max
__global__ __launch_bounds__(256)
void kwmm(const float* __restrict__ W, const float* __restrict__ scale,
          unsigned* __restrict__ enc)
{
  const int idx = blockIdx.x * 256 + threadIdx.x;
  float v = 0.f;
  if (idx < NWELEM) v = W[idx] * scale[idx & 255];
  float mn = v, mx = v;
  #pragma unroll
  for (int off = 32; off > 0; off >>= 1) {
    mn = fminf(mn, __shfl_xor(mn, off));
    mx = fmaxf(mx, __shfl_xor(mx, off));
  }
  __shared__ float rmn[4], rmx[4];
  const int lane = threadIdx.x & 63, w = threadIdx.x >> 6;
  if (lane == 0) { rmn[w] = mn; rmx[w] = mx; }
  __syncthreads();
  if (threadIdx.x == 0) {
    mn = fminf(fminf(rmn[0], rmn[1]), fminf(rmn[2], rmn[3]));
    mx = fmaxf(fmaxf(rmx[0], rmx[1]), fmaxf(rmx[2], rmx[3]));
    atomicMin(&enc[2], encf(mn));
    atomicMax(&enc[3], encf(mx));
  }
}

extern "C" void kernel_launch(void* const* d_in, const int* in_sizes, int n_in,
                              void* d_out, int out_size, void* d_ws, size_t ws_size,
                              hipStream_t stream)
{
  const float* x     = (const float*)d_in[0];
  const float* W     = (const float*)d_in[1];
  const float* gamma = (const float*)d_in[2];
  const float* beta  = (const float*)d_in[3];
  float* out = (float*)d_out;
  char* ws = (char*)d_ws;

  unsigned* enc        = (unsigned*)(ws + OFF_ENC);
  float* scale         = (float*)(ws + OFF_SCALE);
  float* bias          = (float*)(ws + OFF_BIAS);
  float* j1tap         = (float*)(ws + OFF_J1TAP);
  float* j1all         = (float*)(ws + OFF_J1ALL);
  unsigned short* Wt   = (unsigned short*)(ws + OFF_WT);
  signed char* wq8     = (signed char*)(ws + OFF_WQT8);
  float* psum          = (float*)(ws + OFF_PSUM);
  float* psq           = (float*)(ws + OFF_PSQ);
  float* k1            = (float*)(ws + OFF_K1);
  float* scp           = (float*)(ws + OFF_SCP);
  unsigned short* xpad = (unsigned short*)(ws + OFF_XPAD);
  signed char* xq8     = (signed char*)(ws + OFF_XQ8);

  kinit<<<1, 64, 0, stream>>>(enc);
  kminmax<<<1024, 256, 0, stream>>>((const float4*)x, enc);
  kwconv<<<1152, 256, 0, stream>>>(W, Wt);
  kpadfill<<<6728, 256, 0, stream>>>(x, enc, xpad, xq8, scp);
  kbox<<<392, 256, 0, stream>>>(scp, k1);
  kconvS<<<784, 512, 0, stream>>>(xpad, Wt, psum, psq);
  kstats<<<256, 256, 0, stream>>>(psum, psq, gamma, beta, scale, bias);
  kwmm<<<1152, 256, 0, stream>>>(W, scale, enc);
  kwq<<<1152, 256, 0, stream>>>(W, scale, enc, wq8, j1tap);
  kjall<<<1, 256, 0, stream>>>(j1tap, j1all);
  kconv2<<<784, 512, 0, stream>>>(xq8, wq8, out, bias, k1, j1tap, j1all, enc);
}

// Round 10
// 237.953 us; speedup vs baseline: 1.0676x; 1.0676x over previous
//
#include <hip/hip_runtime.h>

typedef float f32x4_t __attribute__((ext_vector_type(4)));
typedef __bf16 bf16x8_t __attribute__((ext_vector_type(8)));
typedef unsigned short u16x8_t __attribute__((ext_vector_type(8)));

// ---- geometry ----
#define NPIX        100352      // 32*56*56
#define PIX_PER_IMG 3136        // 56*56
#define PH          58
#define PPIX        3364        // 58*58
#define C_IN        128
#define C_OUT       256
#define NV4         3211264     // x as float4 count
#define NWELEM      294912      // 3*3*128*256
#define MTILES      392         // NPIX/256
#define NPADPIX     107648      // 32*58*58

// ---- ws byte offsets ----
#define OFF_ENC     0           // 4 x u32 (x min/max, wfold min/max encodings)
#define OFF_SCALE   64          // 256 f32
#define OFF_BIAS    1152        // 256 f32
#define OFF_WT      4096        // 589824 B bf16 [9][256 f][128 c]
#define OFF_WQT     593920      // 589824 B
#define OFF_PSUM    1183744     // 784*128 f32
#define OFF_PSQ     1986560     // 784*128 f32
#define OFF_XPAD    2789376     // 27557888 B bf16 [32][58][58][128]
#define OFF_XQPAD   30347264    // 27557888 B   (end: 57905152)

// ---- helpers ----
__device__ __forceinline__ unsigned short f2bf(float x) {
  unsigned u = __float_as_uint(x);
  u += 0x7FFFu + ((u >> 16) & 1u);   // RNE
  return (unsigned short)(u >> 16);
}
__device__ __forceinline__ unsigned encf(float v) {
  unsigned u = __float_as_uint(v);
  return (u & 0x80000000u) ? ~u : (u | 0x80000000u);
}
__device__ __forceinline__ float decf(unsigned e) {
  unsigned u = (e & 0x80000000u) ? (e ^ 0x80000000u) : ~e;
  return __uint_as_float(u);
}
__device__ __forceinline__ void gl_lds16(const void* g, void* l) {
  auto gp = (const __attribute__((address_space(1))) unsigned*)(const unsigned*)g;
  auto lp = (__attribute__((address_space(3))) unsigned*)(unsigned*)l;
  __builtin_amdgcn_global_load_lds(gp, lp, 16, 0, 0);
}
#define SCHED_FENCE() __builtin_amdgcn_sched_barrier(0)

// ---- kernels ----
__global__ void kinit(unsigned* enc) {
  enc[0] = 0xFFFFFFFFu; enc[1] = 0u;   // x min/max encodings
  enc[2] = 0xFFFFFFFFu; enc[3] = 0u;   // wfold min/max encodings
}

__global__ void kminmax(const float4* __restrict__ x, unsigned* __restrict__ enc) {
  const int tid = blockIdx.x * blockDim.x + threadIdx.x;
  const int stride = gridDim.x * blockDim.x;
  float mn = 3.4e38f, mx = -3.4e38f;
  for (int i = tid; i < NV4; i += stride) {
    float4 v = x[i];
    mn = fminf(mn, fminf(fminf(v.x, v.y), fminf(v.z, v.w)));
    mx = fmaxf(mx, fmaxf(fmaxf(v.x, v.y), fmaxf(v.z, v.w)));
  }
  #pragma unroll
  for (int off = 32; off > 0; off >>= 1) {
    mn = fminf(mn, __shfl_xor(mn, off));
    mx = fmaxf(mx, __shfl_xor(mx, off));
  }
  __shared__ float smn[4], smx[4];
  const int lane = threadIdx.x & 63, w = threadIdx.x >> 6;
  if (lane == 0) { smn[w] = mn; smx[w] = mx; }
  __syncthreads();
  if (threadIdx.x == 0) {
    mn = fminf(fminf(smn[0], smn[1]), fminf(smn[2], smn[3]));
    mx = fmaxf(fmaxf(smx[0], smx[1]), fmaxf(smx[2], smx[3]));
    atomicMin(&enc[0], encf(mn));
    atomicMax(&enc[1], encf(mx));
  }
}

// W [3][3][128][256] f32 -> Wt [tap][256 f][128 c] bf16
__global__ void kwconv(const float* __restrict__ W, unsigned short* __restrict__ wt) {
  const int idx = blockIdx.x * 256 + threadIdx.x;
  if (idx >= NWELEM) return;
  const int c = idx & 127;
  const int f = (idx >> 7) & 255;
  const int tap = idx >> 15;
  wt[idx] = f2bf(W[(tap * 128 + c) * 256 + f]);
}

// quantized folded weights, same layout
__global__ void kwq(const float* __restrict__ W, const float* __restrict__ scale,
                    const unsigned* __restrict__ enc, unsigned short* __restrict__ wqt) {
  const int idx = blockIdx.x * 256 + threadIdx.x;
  if (idx >= NWELEM) return;
  const int c = idx & 127;
  const int f = (idx >> 7) & 255;
  const int tap = idx >> 15;
  const float wmn = decf(enc[2]), wmx = decf(enc[3]);
  const float wstep = (wmx - wmn) / 255.0f;
  const float wrstep = 255.0f / (wmx - wmn);
  const float v = W[(tap * 128 + c) * 256 + f] * scale[f];
  const float q = rintf((v - wmn) * wrstep) * wstep + wmn;
  wqt[idx] = f2bf(q);
}

// pad-fill: x f32 -> xpad bf16 (zero border) and xqpad bf16 (quantized, zero border)
__global__ void kpadfill(const float* __restrict__ x, const unsigned* __restrict__ enc,
                         unsigned short* __restrict__ xpad, unsigned short* __restrict__ xqpad)
{
  const int tid = blockIdx.x * 256 + threadIdx.x;
  if (tid >= NPADPIX * 16) return;
  const int pp = tid >> 4;
  const int c8 = (tid & 15) << 3;
  const int n = pp / PPIX;
  const int rem = pp - n * PPIX;
  const int hp = rem / PH;
  const int wp = rem - hp * PH;
  u16x8_t vb, vq;
  #pragma unroll
  for (int j = 0; j < 8; ++j) { vb[j] = 0; vq[j] = 0; }
  if (hp >= 1 && hp <= 56 && wp >= 1 && wp <= 56) {
    const float mn = decf(enc[0]), mx = decf(enc[1]);
    const float step = (mx - mn) / 255.0f, rstep = 255.0f / (mx - mn);
    const float* src = x + ((n * PIX_PER_IMG) + (hp - 1) * 56 + (wp - 1)) * C_IN + c8;
    const float4 a = *(const float4*)src;
    const float4 b = *(const float4*)(src + 4);
    const float v[8] = {a.x, a.y, a.z, a.w, b.x, b.y, b.z, b.w};
    #pragma unroll
    for (int j = 0; j < 8; ++j) {
      vb[j] = f2bf(v[j]);
      const float qv = rintf((v[j] - mn) * rstep) * step + mn;
      vq[j] = f2bf(qv);
    }
  }
  *(u16x8_t*)(xpad + pp * C_IN + c8) = vb;
  *(u16x8_t*)(xqpad + pp * C_IN + c8) = vq;
}

// implicit-GEMM conv. BM=256, BN=128 (bn = N-half), BK=32. 512 threads, 8 waves
// 4(M)x2(N), wave tile 64x64. LDS = 3-slot ring x 24KB (A 16K + B 8K) = 72KB,
// 2 blocks/CU. ONE barrier per K-tile: {vmcnt(3); barrier; stage(t+2) into slot
// (t+2)%3 (legal: != slot being read, and the barrier proves tile t-1's reads are
// done); 8 ds_read; 16 MFMA}. Anti-phase: block parity rotates the commutative
// K-tile order by half. XOR chunk swizzle both-sides (rule #21) as R8.
// STATS=1: per-block column sum/sumsq partials. STATS=0: out = relu(conv + bias).
template<int STATS>
__global__ __launch_bounds__(512, 4)
void kconv(const unsigned short* __restrict__ xin,   // padded bf16 [32][58][58][128]
           const unsigned short* __restrict__ wt,    // bf16 [9][256 f][128 c]
           float* __restrict__ out,
           const float* __restrict__ bias,
           float* __restrict__ psum,
           float* __restrict__ psq)
{
  // XCD-aware bijective swizzle: 784 = 8*98; (bm,0)/(bm,1) adjacent on same XCD.
  const int bid = blockIdx.x;
  const int slot = (bid & 7) * 98 + (bid >> 3);   // 0..783
  const int bm = slot >> 1;                        // 0..391
  const int bn = slot & 1;                         // N-half
  const int rot = (bid & 1) * 18;                  // anti-phase tile rotation

  const int tid = threadIdx.x;
  const int lane = tid & 63;
  const int wid = tid >> 6;
  const int wm = wid >> 1;          // 0..3
  const int wn = wid & 1;           // 0..1
  const int l16 = lane & 15;
  const int rsub = lane >> 4;

  __shared__ __align__(16) unsigned char smem[73728];   // 3 x (A 16KB + B 8KB)

  // ---- staging offsets (global source pre-swizzled; LDS dest linear) ----
  unsigned aoff[2];
  {
    const int arow0 = wid * 8 + (lane >> 3);
    const int pc = lane & 7;
    #pragma unroll
    for (int j = 0; j < 2; ++j) {
      const int row = j * 64 + arow0;
      const int lc = pc ^ (row & 7);
      const int pix = bm * 256 + row + 128 * (lc >> 2);
      const int n = pix / PIX_PER_IMG;
      const int rem = pix - n * PIX_PER_IMG;
      const int hh = rem / 56;
      const int ww = rem - hh * 56;
      aoff[j] = (unsigned)((n * PPIX + hh * PH + ww) * C_IN + (lc & 3) * 8);
    }
  }
  unsigned boff;
  {
    const int row = wid * 8 + (lane >> 3);
    const int pc = lane & 7;
    const int lc = pc ^ (row & 7);
    const int f = bn * 128 + row + 64 * (lc >> 2);
    boff = (unsigned)(f * C_IN + (lc & 3) * 8);
  }

  // ---- ds_read byte offsets (within a ring slot) ----
  int a_rd[4], b_rd[4];
  #pragma unroll
  for (int im = 0; im < 4; ++im) {
    const int p = wm * 64 + im * 16 + l16;          // pixel in tile, 0..255
    const int row = p & 127, half = p >> 7;
    const int phys = (half * 4 + rsub) ^ (row & 7);
    a_rd[im] = row * 128 + phys * 16;
  }
  #pragma unroll
  for (int in = 0; in < 4; ++in) {
    const int f = wn * 64 + in * 16 + l16;          // f in tile, 0..127
    const int row = f & 63, half = f >> 6;
    const int phys = (half * 4 + rsub) ^ (row & 7);
    b_rd[in] = row * 128 + phys * 16;
  }

  f32x4_t acc[4][4];
  #pragma unroll
  for (int im = 0; im < 4; ++im)
    #pragma unroll
    for (int in = 0; in < 4; ++in)
      #pragma unroll
      for (int j = 0; j < 4; ++j) acc[im][in][j] = 0.f;

  // stage logical tile s into ring slot s%3 (3 loads/thread); physical tile rotated
  auto stage = [&](int s) {
    int pt = s + rot; if (pt >= 36) pt -= 36;
    const int tap = pt >> 2;
    const int cq = (pt & 3) * 32;
    const int kh = tap / 3, kw = tap - kh * 3;
    const unsigned atap = (unsigned)((kh * PH + kw) * C_IN + cq);
    const unsigned btap = (unsigned)(tap * (C_OUT * C_IN) + cq);
    unsigned char* sA = smem + (s % 3) * 24576;
    unsigned char* sB = sA + 16384;
    gl_lds16(xin + atap + aoff[0], sA + wid * 1024);
    gl_lds16(xin + atap + aoff[1], sA + 8192 + wid * 1024);
    gl_lds16(wt + btap + boff, sB + wid * 1024);
  };

  auto compute = [&](int s) {
    const unsigned char* sA = smem + (s % 3) * 24576;
    const unsigned char* sB = sA + 16384;
    bf16x8_t av[4], bv[4];
    #pragma unroll
    for (int im = 0; im < 4; ++im) av[im] = *(const bf16x8_t*)(sA + a_rd[im]);
    #pragma unroll
    for (int in = 0; in < 4; ++in) bv[in] = *(const bf16x8_t*)(sB + b_rd[in]);
    #pragma unroll
    for (int im = 0; im < 4; ++im)
      #pragma unroll
      for (int in = 0; in < 4; ++in)
        acc[im][in] = __builtin_amdgcn_mfma_f32_16x16x32_bf16(av[im], bv[in], acc[im][in], 0, 0, 0);
  };

  stage(0);
  stage(1);

  // 36 K-tiles (9 taps x 4 channel-quarters), single barrier per tile.
  #pragma unroll 1
  for (int s = 0; s < 36; ++s) {
    if (s < 35) asm volatile("s_waitcnt vmcnt(3)" ::: "memory");   // tile s landed
    else        asm volatile("s_waitcnt vmcnt(0)" ::: "memory");
    SCHED_FENCE();
    __builtin_amdgcn_s_barrier();   // all waves: s staged + s-1 reads done
    SCHED_FENCE();
    if (s < 34) stage(s + 2);       // slot (s+2)%3 == slot (s-1)%3, now free
    compute(s);
  }

  if (STATS) {
    __syncthreads();
    float* sb = (float*)smem;      // [8 waves][64 cols] sums; sumsq at +512
    #pragma unroll
    for (int in = 0; in < 4; ++in) {
      float s = 0.f, q = 0.f;
      #pragma unroll
      for (int im = 0; im < 4; ++im)
        #pragma unroll
        for (int j = 0; j < 4; ++j) {
          const float v = acc[im][in][j];
          s += v; q += v * v;
        }
      s += __shfl_xor(s, 16); q += __shfl_xor(q, 16);
      s += __shfl_xor(s, 32); q += __shfl_xor(q, 32);
      if (lane < 16) {
        sb[wid * 64 + in * 16 + lane] = s;
        sb[512 + wid * 64 + in * 16 + lane] = q;
      }
    }
    __syncthreads();
    if (tid < 128) {
      const int wn2 = tid >> 6, cl = tid & 63;   // channel c = wn2*64 + cl
      float s = 0.f, q = 0.f;
      #pragma unroll
      for (int wm2 = 0; wm2 < 4; ++wm2) {
        s += sb[(wm2 * 2 + wn2) * 64 + cl];
        q += sb[512 + (wm2 * 2 + wn2) * 64 + cl];
      }
      psum[(bm * 2 + bn) * 128 + tid] = s;
      psq[(bm * 2 + bn) * 128 + tid] = q;
    }
  } else {
    float bval[4];
    #pragma unroll
    for (int in = 0; in < 4; ++in)
      bval[in] = bias[bn * 128 + wn * 64 + in * 16 + l16];
    #pragma unroll
    for (int im = 0; im < 4; ++im) {
      #pragma unroll
      for (int j = 0; j < 4; ++j) {
        const int pix = bm * 256 + wm * 64 + im * 16 + rsub * 4 + j;
        #pragma unroll
        for (int in = 0; in < 4; ++in) {
          const int f = bn * 128 + wn * 64 + in * 16 + l16;
          out[pix * 256 + f] = fmaxf(acc[im][in][j] + bval[in], 0.f);
        }
      }
    }
  }
}

// per-channel stats: one block per channel
__global__ __launch_bounds__(256)
void kstats(const float* __restrict__ psum, const float* __restrict__ psq,
            const float* __restrict__ gamma, const float* __restrict__ beta,
            float* __restrict__ scale, float* __restrict__ bias)
{
  const int ch = blockIdx.x;
  const int bn = ch >> 7, col = ch & 127;
  float s = 0.f, q = 0.f;
  for (int bm = threadIdx.x; bm < MTILES; bm += 256) {
    s += psum[(bm * 2 + bn) * 128 + col];
    q += psq[(bm * 2 + bn) * 128 + col];
  }
  #pragma unroll
  for (int off = 32; off > 0; off >>= 1) {
    s += __shfl_xor(s, off);
    q += __shfl_xor(q, off);
  }
  __shared__ float ss[4], sq2[4];
  const int lane = threadIdx.x & 63, w = threadIdx.x >> 6;
  if (lane == 0) { ss[w] = s; sq2[w] = q; }
  __syncthreads();
  if (threadIdx.x == 0) {
    s = ss[0] + ss[1] + ss[2] + ss[3];
    q = sq2[0] + sq2[1] + sq2[2] + sq2[3];
    const float inv = 1.0f / (float)NPIX;
    const float mean = s * inv;
    const float var = q * inv - mean * mean;
    const float istd = 1.0f / sqrtf(var + 1e-5f);
    const float g = gamma[ch];
    scale[ch] = g * istd;
    bias[ch] = beta[ch] - g * mean * istd;
  }
}

// w_fold min/max, parallel over all elements
__global__ __launch_bounds__(256)
void kwmm(const float* __restrict__ W, const float* __restrict__ scale,
          unsigned* __restrict__ enc)
{
  const int idx = blockIdx.x * 256 + threadIdx.x;
  float v = 0.f;
  if (idx < NWELEM) v = W[idx] * scale[idx & 255];   // last dim of W is f (256)
  float mn = v, mx = v;
  #pragma unroll
  for (int off = 32; off > 0; off >>= 1) {
    mn = fminf(mn, __shfl_xor(mn, off));
    mx = fmaxf(mx, __shfl_xor(mx, off));
  }
  __shared__ float rmn[4], rmx[4];
  const int lane = threadIdx.x & 63, w = threadIdx.x >> 6;
  if (lane == 0) { rmn[w] = mn; rmx[w] = mx; }
  __syncthreads();
  if (threadIdx.x == 0) {
    mn = fminf(fminf(rmn[0], rmn[1]), fminf(rmn[2], rmn[3]));
    mx = fmaxf(fmaxf(rmx[0], rmx[1]), fmaxf(rmx[2], rmx[3]));
    atomicMin(&enc[2], encf(mn));
    atomicMax(&enc[3], encf(mx));
  }
}

extern "C" void kernel_launch(void* const* d_in, const int* in_sizes, int n_in,
                              void* d_out, int out_size, void* d_ws, size_t ws_size,
                              hipStream_t stream)
{
  const float* x     = (const float*)d_in[0];
  const float* W     = (const float*)d_in[1];
  const float* gamma = (const float*)d_in[2];
  const float* beta  = (const float*)d_in[3];
  float* out = (float*)d_out;
  char* ws = (char*)d_ws;

  unsigned* enc        = (unsigned*)(ws + OFF_ENC);
  float* scale         = (float*)(ws + OFF_SCALE);
  float* bias          = (float*)(ws + OFF_BIAS);
  unsigned short* Wt   = (unsigned short*)(ws + OFF_WT);
  unsigned short* Wqt  = (unsigned short*)(ws + OFF_WQT);
  float* psum          = (float*)(ws + OFF_PSUM);
  float* psq           = (float*)(ws + OFF_PSQ);
  unsigned short* xpad  = (unsigned short*)(ws + OFF_XPAD);
  unsigned short* xqpad = (unsigned short*)(ws + OFF_XQPAD);

  kinit<<<1, 64, 0, stream>>>(enc);
  kminmax<<<1024, 256, 0, stream>>>((const float4*)x, enc);
  kwconv<<<1152, 256, 0, stream>>>(W, Wt);
  kpadfill<<<6728, 256, 0, stream>>>(x, enc, xpad, xqpad);
  kconv<1><<<784, 512, 0, stream>>>(xpad, Wt, nullptr, nullptr, psum, psq);
  kstats<<<256, 256, 0, stream>>>(psum, psq, gamma, beta, scale, bias);
  kwmm<<<1152, 256, 0, stream>>>(W, scale, enc);
  kwq<<<1152, 256, 0, stream>>>(W, scale, enc, Wqt);
  kconv<0><<<784, 512, 0, stream>>>(xqpad, Wqt, out, bias, nullptr, nullptr);
}